// Round 1
// baseline (11525.198 us; speedup 1.0000x reference)
//
#include <hip/hip_runtime.h>
#include <math.h>

// NodeformerProcessor: 3x (nodeformer_conv -> [leaky] -> graph_norm), full fp64.
// Numerics: final output ~2e-12 arises from ~1e-6-relative deviations of
// nearly-identical rows; threshold is 2% relative vs an fp64 np reference,
// so every stage runs in double precision. All reductions are fixed-order
// (no atomics) -> deterministic across graph replays.

namespace {

constexpr int N    = 50000;   // nodes
constexpr int C    = 64;      // channels (= head dim)
constexpr int H    = 8;       // heads
constexpr int HD   = 512;     // H*C
constexpr int M    = 30;      // random features
constexpr int NT   = 4;       // nodes per group (N % NT == 0)
constexpr int NGRP = N / NT;  // 12500
constexpr int NB_A = 512;     // blocks, stab pass
constexpr int NB2  = 64;      // blocks per head, kv pass
constexpr int NB_E = 512;     // blocks, q pass
constexpr int PSTRIDE = M * 64 + 32; // 1952 doubles per kv partial

__device__ constexpr double DN    = 0.35355339059327373;  // 1/sqrt(sqrt(64))
__device__ constexpr double RATIO = 0.18257418583505536;  // 1/sqrt(30)
__device__ constexpr double EPSK  = 1e-6;
__device__ constexpr double EPSN  = 1e-5;

// ---------------- convert f32 -> f64 ----------------
__global__ void k_convert(const float* __restrict__ in, double* __restrict__ out, int total) {
  for (int i = blockIdx.x * blockDim.x + threadIdx.x; i < total; i += gridDim.x * blockDim.x)
    out[i] = (double)in[i];
}

// ---------------- pass A: per-head global max of dd_k ----------------
__global__ __launch_bounds__(256)
void k_stab(const double* __restrict__ x, const float* __restrict__ Wk,
            const float* __restrict__ bk, const float* __restrict__ P,
            double* __restrict__ pmax) {
  __shared__ double xs[NT][C];
  __shared__ double ks[NT][HD];
  __shared__ double ddl[NT][H * M];
  __shared__ double red[NT][H];
  const int t = threadIdx.x;
  const int i0 = t >> 6, c0 = t & 63;
  double runmax = -1e300;  // threads t<32: slot (i=t>>3, h=t&7)

  for (int g = blockIdx.x; g < NGRP; g += gridDim.x) {
    const int n0 = g * NT;
    __syncthreads();
    xs[i0][c0] = x[(size_t)(n0 + i0) * C + c0];
    __syncthreads();
    // k = x @ Wk + bk  (each thread: 8 outputs j = c0 + 64*kk)
    double acc[8];
#pragma unroll
    for (int kk = 0; kk < 8; ++kk) acc[kk] = (double)bk[c0 + 64 * kk];
    for (int c = 0; c < C; ++c) {
      const double xv = xs[i0][c];
#pragma unroll
      for (int kk = 0; kk < 8; ++kk)
        acc[kk] = fma(xv, (double)Wk[c * HD + c0 + 64 * kk], acc[kk]);
    }
#pragma unroll
    for (int kk = 0; kk < 8; ++kk) ks[i0][c0 + 64 * kk] = acc[kk];
    __syncthreads();
    // dd_k[i][h,m] = DN * sum_d k[i][h*64+d] * P[m][d]
    for (int s = t; s < NT * H * M; s += 256) {
      const int i = s / (H * M), hm = s % (H * M), h = hm / M, m = hm % M;
      double a = 0.0;
      for (int d = 0; d < C; ++d)
        a = fma(ks[i][h * 64 + d], (double)P[m * C + d], a);
      ddl[i][hm] = a * DN;
    }
    __syncthreads();
    if (t < NT * H) {
      const int i = t >> 3, h = t & 7;
      double mx = ddl[i][h * M];
      for (int m = 1; m < M; ++m) mx = fmax(mx, ddl[i][h * M + m]);
      runmax = fmax(runmax, mx);
    }
  }
  __syncthreads();
  if (t < NT * H) red[t >> 3][t & 7] = runmax;
  __syncthreads();
  if (t < H) {
    double mx = red[0][t];
    for (int i = 1; i < NT; ++i) mx = fmax(mx, red[i][t]);
    pmax[(size_t)blockIdx.x * H + t] = mx;
  }
}

__global__ void k_redstab(const double* __restrict__ pmax, double* __restrict__ stabk, int nb) {
  const int t = threadIdx.x;
  if (t < H) {
    double mx = pmax[t];
    for (int b = 1; b < nb; ++b) mx = fmax(mx, pmax[(size_t)b * H + t]);
    stabk[t] = mx;
  }
}

// ---------------- pass C: kvs / ksum partials (per head) ----------------
__global__ __launch_bounds__(256)
void k_kv(const double* __restrict__ x, const float* __restrict__ Wk, const float* __restrict__ bk,
          const float* __restrict__ Wv, const float* __restrict__ bv,
          const float* __restrict__ P, const double* __restrict__ stabk,
          double* __restrict__ partial) {
  const int blk = blockIdx.x;
  const int h = blk / NB2, b = blk % NB2;
  const int hbase = h * 64;
  __shared__ double xs[NT][C];
  __shared__ double ks[NT][C];
  __shared__ double vs[NT][C];
  __shared__ double kpl[NT][M];
  __shared__ double diag[NT];
  const int t = threadIdx.x;
  const int i0 = t >> 6, c0 = t & 63;
  const double stab = stabk[h];
  double acc8[8];
#pragma unroll
  for (int k = 0; k < 8; ++k) acc8[k] = 0.0;
  double ksacc = 0.0;

  for (int g = b; g < NGRP; g += NB2) {
    const int n0 = g * NT;
    __syncthreads();
    xs[i0][c0] = x[(size_t)(n0 + i0) * C + c0];
    __syncthreads();
    // k,v for this head only
    double ka = (double)bk[hbase + c0];
    double va = (double)bv[hbase + c0];
    for (int c = 0; c < C; ++c) {
      const double xv = xs[i0][c];
      ka = fma(xv, (double)Wk[c * HD + hbase + c0], ka);
      va = fma(xv, (double)Wv[c * HD + hbase + c0], va);
    }
    ks[i0][c0] = ka;
    vs[i0][c0] = va;
    __syncthreads();
    if (t < NT * M) {  // dd_k
      const int i = t / M, m = t % M;
      double a = 0.0;
      for (int d = 0; d < C; ++d) a = fma(ks[i][d], (double)P[m * C + d], a);
      kpl[i][m] = a * DN;
    }
    if (t >= 128 && t < 128 + NT) {  // diag_k
      const int i = t - 128;
      double ss = 0.0;
      for (int d = 0; d < C; ++d) { const double kk = ks[i][d]; ss = fma(kk, kk, ss); }
      diag[i] = ss * (DN * DN * 0.5);
    }
    __syncthreads();
    if (t < NT * M) {
      const int i = t / M, m = t % M;
      kpl[i][m] = RATIO * (exp((kpl[i][m] - diag[i]) - stab) + EPSK);
    }
    __syncthreads();
    // accumulate kvs[m][d] += kp[i][m]*v[i][d] into registers (d = c0 fixed per thread)
    double vr[NT];
#pragma unroll
    for (int i = 0; i < NT; ++i) vr[i] = vs[i][c0];
#pragma unroll
    for (int k = 0; k < 8; ++k) {
      const int s = t + k * 256;
      if (s < M * 64) {
        const int m = s >> 6;
        double a = acc8[k];
#pragma unroll
        for (int i = 0; i < NT; ++i) a = fma(kpl[i][m], vr[i], a);
        acc8[k] = a;
      }
    }
    if (t < M) {
      double a = ksacc;
#pragma unroll
      for (int i = 0; i < NT; ++i) a += kpl[i][t];
      ksacc = a;
    }
  }
  const size_t base = (size_t)blk * PSTRIDE;
#pragma unroll
  for (int k = 0; k < 8; ++k) {
    const int s = t + k * 256;
    if (s < M * 64) partial[base + s] = acc8[k];
  }
  if (t < M) partial[base + M * 64 + t] = ksacc;
}

__global__ void k_redkv(const double* __restrict__ partial, double* __restrict__ kvsg,
                        double* __restrict__ ksumg) {
  const int h = blockIdx.x, t = threadIdx.x;
  for (int s = t; s < M * 64 + M; s += 256) {
    double a = 0.0;
    for (int b = 0; b < NB2; ++b)
      a += partial[(size_t)(h * NB2 + b) * PSTRIDE + s];
    if (s < M * 64) kvsg[(size_t)h * (M * 64) + s] = a;
    else            ksumg[h * M + (s - M * 64)] = a;
  }
}

// ---------------- pass E: q / qp / z / out / column sums ----------------
__global__ __launch_bounds__(256)
void k_q(const double* __restrict__ x, const float* __restrict__ Wq, const float* __restrict__ bq,
         const float* __restrict__ P, const double* __restrict__ kvsg,
         const double* __restrict__ ksumg, const float* __restrict__ Wo,
         const float* __restrict__ bo, int do_leaky,
         double* __restrict__ y, double* __restrict__ psum) {
  __shared__ double xs[NT][C];
  __shared__ double qs[NT][HD];
  __shared__ double qps[NT][H * M];
  __shared__ double zs[NT][HD];
  __shared__ double stabl[NT][H], diagl[NT][H], rdenl[NT][H];
  const int t = threadIdx.x;
  const int i0 = t >> 6, c0 = t & 63;
  double sy = 0.0, sy2 = 0.0;

  for (int g = blockIdx.x; g < NGRP; g += gridDim.x) {
    const int n0 = g * NT;
    __syncthreads();
    xs[i0][c0] = x[(size_t)(n0 + i0) * C + c0];
    __syncthreads();
    // q = x @ Wq + bq
    double acc[8];
#pragma unroll
    for (int kk = 0; kk < 8; ++kk) acc[kk] = (double)bq[c0 + 64 * kk];
    for (int c = 0; c < C; ++c) {
      const double xv = xs[i0][c];
#pragma unroll
      for (int kk = 0; kk < 8; ++kk)
        acc[kk] = fma(xv, (double)Wq[c * HD + c0 + 64 * kk], acc[kk]);
    }
#pragma unroll
    for (int kk = 0; kk < 8; ++kk) qs[i0][c0 + 64 * kk] = acc[kk];
    __syncthreads();
    // dd_q
    for (int s = t; s < NT * H * M; s += 256) {
      const int i = s / (H * M), hm = s % (H * M), h = hm / M, m = hm % M;
      double a = 0.0;
      for (int d = 0; d < C; ++d)
        a = fma(qs[i][h * 64 + d], (double)P[m * C + d], a);
      qps[i][hm] = a * DN;
    }
    __syncthreads();
    // per-(i,h) stab (local max) + diag
    if (t < NT * H) {
      const int i = t >> 3, h = t & 7;
      double mx = qps[i][h * M];
      for (int m = 1; m < M; ++m) mx = fmax(mx, qps[i][h * M + m]);
      double ss = 0.0;
      for (int d = 0; d < C; ++d) { const double q = qs[i][h * 64 + d]; ss = fma(q, q, ss); }
      stabl[i][h] = mx;
      diagl[i][h] = ss * (DN * DN * 0.5);
    }
    __syncthreads();
    // qp
    for (int s = t; s < NT * H * M; s += 256) {
      const int i = s / (H * M), hm = s % (H * M), h = hm / M;
      qps[i][hm] = RATIO * (exp((qps[i][hm] - diagl[i][h]) - stabl[i][h]) + EPSK);
    }
    __syncthreads();
    // den
    if (t < NT * H) {
      const int i = t >> 3, h = t & 7;
      double a = 0.0;
      for (int m = 0; m < M; ++m) a = fma(qps[i][h * M + m], ksumg[h * M + m], a);
      rdenl[i][h] = 1.0 / a;
    }
    __syncthreads();
    // num / z
#pragma unroll
    for (int k = 0; k < 8; ++k) {
      const int s = t + k * 256;          // 0..2047 exactly
      const int i = s >> 9, hd = s & 511, h = hd >> 6, d = hd & 63;
      double a = 0.0;
      for (int m = 0; m < M; ++m)
        a = fma(qps[i][h * M + m], kvsg[(size_t)(h * M + m) * 64 + d], a);
      zs[i][hd] = a * rdenl[i][h];
    }
    __syncthreads();
    // out = z @ Wo + bo, leaky, store, accumulate column sums
    {
      double a = (double)bo[c0];
      for (int j = 0; j < HD; ++j)
        a = fma(zs[i0][j], (double)Wo[j * 64 + c0], a);
      if (do_leaky) a = (a >= 0.0) ? a : 0.01 * a;
      y[(size_t)(n0 + i0) * C + c0] = a;
      sy += a;
      sy2 = fma(a, a, sy2);
    }
  }
  // block-level column reduction (4 node-slots share column c0)
  __syncthreads();
  xs[i0][c0] = sy;
  __syncthreads();
  if (t < C) psum[(size_t)blockIdx.x * 128 + t] = xs[0][t] + xs[1][t] + xs[2][t] + xs[3][t];
  __syncthreads();
  xs[i0][c0] = sy2;
  __syncthreads();
  if (t < C) psum[(size_t)blockIdx.x * 128 + 64 + t] = xs[0][t] + xs[1][t] + xs[2][t] + xs[3][t];
}

// ---------------- graph-norm parameters ----------------
__global__ void k_norm_params(const double* __restrict__ psum, int nb,
                              const float* __restrict__ gamma, const float* __restrict__ beta,
                              const float* __restrict__ alpha, double* __restrict__ nparam) {
  const int t = threadIdx.x;
  if (t < C) {
    double s1 = 0.0, s2 = 0.0;
    for (int b = 0; b < nb; ++b) {
      s1 += psum[(size_t)b * 128 + t];
      s2 += psum[(size_t)b * 128 + 64 + t];
    }
    const double mu = s1 / (double)N;
    const double m2 = s2 / (double)N;
    const double al = (double)alpha[t];
    double var = m2 - (2.0 * al - al * al) * mu * mu;
    if (var < 0.0) var = 0.0;   // rounding guard; |delta| ~1e-20, var+eps >= 1e-5
    nparam[t]       = al * mu;
    nparam[64 + t]  = (double)gamma[t] / sqrt(var + EPSN);
    nparam[128 + t] = (double)beta[t];
  }
}

// ---------------- apply graph norm ----------------
__global__ void k_normalize(const double* __restrict__ y, const double* __restrict__ nparam,
                            double* __restrict__ xout, float* __restrict__ fout) {
  const int total = N * C;
  for (int i = blockIdx.x * blockDim.x + threadIdx.x; i < total; i += gridDim.x * blockDim.x) {
    const int c = i & 63;
    const double v = (y[i] - nparam[c]) * nparam[64 + c] + nparam[128 + c];
    if (xout) xout[i] = v;
    else      fout[i] = (float)v;
  }
}

}  // namespace

extern "C" void kernel_launch(void* const* d_in, const int* in_sizes, int n_in,
                              void* d_out, int out_size, void* d_ws, size_t ws_size,
                              hipStream_t stream) {
  const float* patch = (const float*)d_in[0];
  // d_in[1] edge_index, d_in[2] edge_attr: unused by the reference
  const float* Wq = (const float*)d_in[3];
  const float* Wk = (const float*)d_in[4];
  const float* Wv = (const float*)d_in[5];
  const float* Wo = (const float*)d_in[6];
  const float* bq = (const float*)d_in[7];
  const float* bk = (const float*)d_in[8];
  const float* bv = (const float*)d_in[9];
  const float* bo = (const float*)d_in[10];
  const float* P  = (const float*)d_in[11];
  const float* ga = (const float*)d_in[12];
  const float* be = (const float*)d_in[13];
  const float* al = (const float*)d_in[14];
  float* out = (float*)d_out;

  // workspace layout (doubles), total ~7.49M doubles ~= 60 MB
  double* ws      = (double*)d_ws;
  double* x       = ws;                                  // N*C
  double* y       = x + (size_t)N * C;                   // N*C
  double* pmax    = y + (size_t)N * C;                   // NB_A*H
  double* stabk   = pmax + (size_t)NB_A * H;             // H
  double* partial = stabk + H;                           // H*NB2*PSTRIDE
  double* kvsg    = partial + (size_t)H * NB2 * PSTRIDE; // H*M*64
  double* ksumg   = kvsg + (size_t)H * M * 64;           // H*M
  double* psum    = ksumg + (size_t)H * M;               // NB_E*128
  double* nparam  = psum + (size_t)NB_E * 128;           // 192

  k_convert<<<256, 256, 0, stream>>>(patch, x, N * C);

  for (int L = 0; L < 3; ++L) {
    const float* wq = Wq + (size_t)L * C * HD;
    const float* wk = Wk + (size_t)L * C * HD;
    const float* wv = Wv + (size_t)L * C * HD;
    const float* wo = Wo + (size_t)L * HD * C;
    const float* bq_ = bq + (size_t)L * HD;
    const float* bk_ = bk + (size_t)L * HD;
    const float* bv_ = bv + (size_t)L * HD;
    const float* bo_ = bo + (size_t)L * C;
    const float* p   = P  + (size_t)L * M * C;

    k_stab<<<NB_A, 256, 0, stream>>>(x, wk, bk_, p, pmax);
    k_redstab<<<1, 64, 0, stream>>>(pmax, stabk, NB_A);
    k_kv<<<H * NB2, 256, 0, stream>>>(x, wk, bk_, wv, bv_, p, stabk, partial);
    k_redkv<<<H, 256, 0, stream>>>(partial, kvsg, ksumg);
    k_q<<<NB_E, 256, 0, stream>>>(x, wq, bq_, p, kvsg, ksumg, wo, bo_,
                                  (L < 2) ? 1 : 0, y, psum);
    k_norm_params<<<1, 64, 0, stream>>>(psum, NB_E, ga + (size_t)L * C,
                                        be + (size_t)L * C, al + (size_t)L * C, nparam);
    k_normalize<<<512, 256, 0, stream>>>(y, nparam,
                                         (L < 2) ? x : nullptr,
                                         (L < 2) ? nullptr : out);
  }
}